// Round 1
// baseline (1674.233 us; speedup 1.0000x reference)
//
#include <hip/hip_runtime.h>

// Problem constants (from setup_inputs: B=16, N=8192, C=256, K_RATIO=0.5)
#define BB 16
#define NN 8192
#define KK 4096
#define CC 256

// -------------------------------------------------------------------------
// Kernel 1: exact top-k via full bitonic sort per batch.
// Key = [monotone-mapped f32 score | (N-1-index)] packed in 64 bits, sorted
// descending -> descending score, ties broken by ascending index (matches
// jax.lax.top_k stable semantics).
// 64 KB LDS, 1024 threads, one block per batch (16 blocks total).
// -------------------------------------------------------------------------
__global__ __launch_bounds__(1024) void topk_sort_kernel(
    const float* __restrict__ scores,
    float* __restrict__ out_idxf,     // [B,K] indices as float (exact <= 8191)
    float* __restrict__ out_scores) { // [B,K]
  __shared__ unsigned long long sh[NN];  // 64 KB
  const int b = blockIdx.x;
  const int tid = threadIdx.x;
  const float* s = scores + (size_t)b * NN;

  for (int t = tid; t < NN; t += 1024) {
    unsigned u = __float_as_uint(s[t]);
    // monotone map: order of u == order of float (total order, -inf..+inf)
    u = (u & 0x80000000u) ? ~u : (u | 0x80000000u);
    sh[t] = ((unsigned long long)u << 32) | (unsigned)(NN - 1 - t);
  }
  __syncthreads();

  for (int k = 2; k <= NN; k <<= 1) {
    for (int j = k >> 1; j > 0; j >>= 1) {
      for (int t = tid; t < NN; t += 1024) {
        int ixj = t ^ j;
        if (ixj > t) {
          unsigned long long a = sh[t];
          unsigned long long c = sh[ixj];
          bool desc = ((t & k) == 0);
          if ((a < c) == desc) { sh[t] = c; sh[ixj] = a; }
        }
      }
      __syncthreads();
    }
  }

  // Emit top-K (first K of descending-sorted keys).
  for (int t = tid; t < KK; t += 1024) {
    unsigned long long key = sh[t];
    int idx = (NN - 1) - (int)(unsigned)(key & 0xFFFFFFFFull);
    out_idxf[(size_t)b * KK + t] = (float)idx;
    out_scores[(size_t)b * KK + t] = s[idx];  // exact original bits
  }
}

// -------------------------------------------------------------------------
// Kernel 2: features row gather. One 64-lane wave per output row, float4.
// 256 threads/block = 4 rows/block. Fully coalesced read+write.
// -------------------------------------------------------------------------
__global__ __launch_bounds__(256) void feat_gather_kernel(
    const float* __restrict__ feat,
    const float* __restrict__ idxf,
    float* __restrict__ out) {
  int r = blockIdx.x * 4 + (threadIdx.x >> 6);  // global output row in [0, B*K)
  int lane = threadIdx.x & 63;
  int b = r >> 12;  // r / K
  int idx = (int)idxf[r];
  const float4* src = (const float4*)(feat + ((size_t)b * NN + idx) * CC);
  float4* dst = (float4*)(out + (size_t)r * CC);
  dst[lane] = src[lane];  // 64 lanes x float4 = 256 floats
}

// -------------------------------------------------------------------------
// Kernel 3: adjacency gather. One block per output row (b,i):
//   stage full 32 KB source row adj[idx_i,:] in LDS (coalesced float4),
//   then out[b,i,j] = lds[idx_j] (coalesced writes, LDS random gather).
// LDS 32 KB -> up to 5 blocks/CU resident.
// -------------------------------------------------------------------------
__global__ __launch_bounds__(256) void adj_gather_kernel(
    const float* __restrict__ adj,
    const float* __restrict__ idxf,
    float* __restrict__ out) {
  __shared__ float srow[NN];  // 32 KB
  int r = blockIdx.x;         // (b,i) flat in [0, B*K)
  int b = r >> 12;
  int irow = (int)idxf[r];

  const float4* row4 = (const float4*)(adj + (size_t)irow * NN);
  float4* srow4 = (float4*)srow;
  #pragma unroll
  for (int p = 0; p < NN / 4 / 256; ++p)
    srow4[p * 256 + threadIdx.x] = row4[p * 256 + threadIdx.x];
  __syncthreads();

  const float* ib = idxf + (size_t)b * KK;
  float* dst = out + (size_t)r * KK;
  #pragma unroll
  for (int q = 0; q < KK / 256; ++q) {
    int j = q * 256 + threadIdx.x;
    dst[j] = srow[(int)ib[j]];
  }
}

extern "C" void kernel_launch(void* const* d_in, const int* in_sizes, int n_in,
                              void* d_out, int out_size, void* d_ws, size_t ws_size,
                              hipStream_t stream) {
  const float* scores = (const float*)d_in[0];  // [B,N]
  const float* feat   = (const float*)d_in[1];  // [B,N,C]
  const float* adj    = (const float*)d_in[2];  // [N,N]

  float* out = (float*)d_out;
  float* out_feat   = out;                                   // B*K*C
  float* out_idxf   = out_feat + (size_t)BB * KK * CC;       // B*K
  float* out_adj    = out_idxf + (size_t)BB * KK;            // B*K*K
  float* out_scores = out_adj + (size_t)BB * KK * KK;        // B*K

  topk_sort_kernel<<<BB, 1024, 0, stream>>>(scores, out_idxf, out_scores);
  feat_gather_kernel<<<BB * KK / 4, 256, 0, stream>>>(feat, out_idxf, out_feat);
  adj_gather_kernel<<<BB * KK, 256, 0, stream>>>(adj, out_idxf, out_adj);
}